// Round 1
// baseline (412.779 us; speedup 1.0000x reference)
//
#include <hip/hip_runtime.h>

typedef unsigned short u16;
typedef __attribute__((ext_vector_type(8))) __bf16 bf16x8;
typedef __attribute__((ext_vector_type(4))) float f32x4;
typedef __attribute__((ext_vector_type(4))) float f4;
typedef __attribute__((ext_vector_type(8))) unsigned short u16x8;
typedef __attribute__((ext_vector_type(4))) unsigned short u16x4;

__device__ __forceinline__ u16 f2bf(float f) {
  union { float f; unsigned int u; } x; x.f = f;
  unsigned int r = x.u + 0x7FFFu + ((x.u >> 16) & 1u);
  return (u16)(r >> 16);
}
__device__ __forceinline__ float bf2f(u16 h) {
  union { unsigned int u; float f; } x; x.u = ((unsigned int)h) << 16;
  return x.f;
}

typedef const __attribute__((address_space(1))) void* gas_t;
typedef __attribute__((address_space(3))) void* las_t;
__device__ __forceinline__ void gload_lds16(const void* g, void* l) {
  __builtin_amdgcn_global_load_lds((gas_t)g, (las_t)l, 16, 0, 0);
}

// ---------------- cast X fp32 -> bf16 ----------------
__global__ __launch_bounds__(256) void k_castx(const float* __restrict__ X, u16* __restrict__ Xb) {
  int i = blockIdx.x * 256 + threadIdx.x;          // 8 floats per thread
  const f4* src = (const f4*)X + (size_t)i * 2;
  f4 a = src[0], b = src[1];
  u16x8 o;
#pragma unroll
  for (int j = 0; j < 4; ++j) { o[j] = f2bf(a[j]); o[4 + j] = f2bf(b[j]); }
  *((u16x8*)Xb + i) = o;
}

// ---------------- transpose+cast W [4096][12288] fp32 -> Wt [12288][4096] bf16 ----
__global__ __launch_bounds__(256) void k_wtrans(const float* __restrict__ W, u16* __restrict__ Wt) {
  const int N = 12288, K = 4096;
  int n0 = blockIdx.x * 64;
  int k0 = blockIdx.y * 64;
  int t = threadIdx.x;
  __shared__ float tile[64][65];
  int tr = t >> 4;           // 0..15
  int tc4 = (t & 15) * 4;    // 0..60
#pragma unroll
  for (int p = 0; p < 4; ++p) {
    int k = k0 + p * 16 + tr;
    f4 v = *(const f4*)&W[(size_t)k * N + n0 + tc4];
#pragma unroll
    for (int j = 0; j < 4; ++j) tile[p * 16 + tr][tc4 + j] = v[j];
  }
  __syncthreads();
#pragma unroll
  for (int p = 0; p < 4; ++p) {
    int n = n0 + p * 16 + tr;
    u16x4 o;
#pragma unroll
    for (int j = 0; j < 4; ++j) o[j] = f2bf(tile[tc4 + j][p * 16 + tr]);
    *(u16x4*)&Wt[(size_t)n * K + k0 + tc4] = o;
  }
}

// ---------------- GEMM: qkv[2048][12288] = Xb @ Wt^T + bias (bf16 out) ----------
__global__ __launch_bounds__(256) void k_gemm(const u16* __restrict__ A, const u16* __restrict__ Bt,
                                              const float* __restrict__ bias, u16* __restrict__ C) {
  const int K = 4096, N = 12288;
  const int bn = blockIdx.x, bm = blockIdx.y;
  const int t = threadIdx.x, w = t >> 6, lane = t & 63;
  const int lr = lane & 15, lg = lane >> 4;
  __shared__ u16 lA[128 * 32];
  __shared__ u16 lB[128 * 32];
  f32x4 acc[4][4] = {};
  const u16* Ag = A + (size_t)bm * 128 * K;
  const u16* Bg = Bt + (size_t)bn * 128 * K;
  const int srow = w * 32 + (lane >> 2);
  const int scol = (lane & 3) * 8;
  for (int kt = 0; kt < K; kt += 32) {
#pragma unroll
    for (int j = 0; j < 2; ++j) {
      int row = srow + j * 16;
      gload_lds16(Ag + (size_t)row * K + kt + scol, &lA[(w * 32 + j * 16) * 32]);
      gload_lds16(Bg + (size_t)row * K + kt + scol, &lB[(w * 32 + j * 16) * 32]);
    }
    __syncthreads();
    bf16x8 af[4], bfr[4];
#pragma unroll
    for (int i = 0; i < 4; ++i) af[i] = *(const bf16x8*)&lA[((w >> 1) * 64 + i * 16 + lr) * 32 + lg * 8];
#pragma unroll
    for (int j = 0; j < 4; ++j) bfr[j] = *(const bf16x8*)&lB[((w & 1) * 64 + j * 16 + lr) * 32 + lg * 8];
#pragma unroll
    for (int i = 0; i < 4; ++i)
#pragma unroll
      for (int j = 0; j < 4; ++j)
        acc[i][j] = __builtin_amdgcn_mfma_f32_16x16x32_bf16(af[i], bfr[j], acc[i][j], 0, 0, 0);
    __syncthreads();
  }
  const int wr = w >> 1, wc = w & 1;
#pragma unroll
  for (int i = 0; i < 4; ++i) {
    int row0 = bm * 128 + wr * 64 + i * 16 + lg * 4;
#pragma unroll
    for (int j = 0; j < 4; ++j) {
      int col = bn * 128 + wc * 64 + j * 16 + lr;
      float bv = bias[col];
#pragma unroll
      for (int r = 0; r < 4; ++r)
        C[(size_t)(row0 + r) * N + col] = f2bf(acc[i][j][r] + bv);
    }
  }
}

// ---------------- RoPE + split/reshape: qkv bf16 -> Q (scaled), K, Vt ----------
__global__ __launch_bounds__(256) void k_rope(const u16* __restrict__ qkv,
                                              u16* __restrict__ Qo, u16* __restrict__ Ko,
                                              u16* __restrict__ Vto) {
  int bid = blockIdx.x;
  int sc = bid & 7, h = (bid >> 3) & 31, b = bid >> 8;
  int t = threadIdx.x;
  int sl = t >> 2, c = t & 3;
  int s = sc * 64 + sl;
  __shared__ u16 vt[128][88];
  const u16* base = qkv + (size_t)(b * 512 + s) * 12288 + h * 384;
  int dbase = c * 32, pbase = dbase ^ 64;
  int j0 = dbase & 63;
  float sgn = (c < 2) ? -1.f : 1.f;
  size_t qkbase = ((size_t)(b * 32 + h) * 512 + s) * 128;
#pragma unroll
  for (int g = 0; g < 4; ++g) {
    u16x8 q1 = *(const u16x8*)(base + dbase + g * 8);
    u16x8 q2 = *(const u16x8*)(base + pbase + g * 8);
    u16x8 k1 = *(const u16x8*)(base + 128 + dbase + g * 8);
    u16x8 k2 = *(const u16x8*)(base + 128 + pbase + g * 8);
    u16x8 vv = *(const u16x8*)(base + 256 + dbase + g * 8);
    u16x8 oq, ok;
#pragma unroll
    for (int i = 0; i < 8; ++i) {
      float j = (float)(j0 + g * 8 + i);
      float ang = (float)s * __expf(j * -0.14391156831f);  // ln(10000)/64
      float sv, cv; __sincosf(ang, &sv, &cv);
      oq[i] = f2bf((bf2f(q1[i]) * cv + sgn * bf2f(q2[i]) * sv) * 0.08838834765f);
      ok[i] = f2bf(bf2f(k1[i]) * cv + sgn * bf2f(k2[i]) * sv);
      vt[dbase + g * 8 + i][sl] = vv[i];
    }
    *(u16x8*)(Qo + qkbase + dbase + g * 8) = oq;
    *(u16x8*)(Ko + qkbase + dbase + g * 8) = ok;
  }
  __syncthreads();
  int d = t & 127, s2 = (t >> 7) * 32;
  size_t vb = ((size_t)(b * 32 + h) * 128 + d) * 512 + sc * 64 + s2;
#pragma unroll
  for (int g = 0; g < 4; ++g)
    *(u16x8*)(Vto + vb + g * 8) = *(const u16x8*)&vt[d][s2 + g * 8];
}

// ---------------- causal flash attention ----------------
__global__ __launch_bounds__(256) void k_attn(const u16* __restrict__ Q, const u16* __restrict__ Kg,
                                              const u16* __restrict__ Vt, float* __restrict__ Out) {
  int bid = blockIdx.x;
  int qb = bid & 3, h = (bid >> 2) & 31, b = bid >> 7;
  int t = threadIdx.x, w = t >> 6, lane = t & 63;
  int lr = lane & 15, lg = lane >> 4;
  size_t bh = (size_t)b * 32 + h;
  const u16* Qp = Q + (bh * 512 + qb * 128) * 128;
  const u16* Kp = Kg + bh * 512 * 128;
  const u16* Vp = Vt + bh * 128 * 512;
  __shared__ u16 lK[64][136];      // padded: 272B rows, 16B aligned
  __shared__ u16 lV[128][88];      // padded: 176B rows
  __shared__ u16 lP[4][16][88];    // per-wave P buffer
  bf16x8 qf[2][4];
#pragma unroll
  for (int mt = 0; mt < 2; ++mt)
#pragma unroll
    for (int dc = 0; dc < 4; ++dc)
      qf[mt][dc] = *(const bf16x8*)(Qp + (size_t)(w * 32 + mt * 16 + lr) * 128 + dc * 32 + lg * 8);
  f32x4 o[2][8] = {};
  float mrow[2][4], lrow[2][4];
#pragma unroll
  for (int mt = 0; mt < 2; ++mt)
#pragma unroll
    for (int r = 0; r < 4; ++r) { mrow[mt][r] = -1e30f; lrow[mt][r] = 0.f; }
  int q0 = qb * 128;
  for (int kv0 = 0; kv0 < q0 + 128; kv0 += 64) {
    __syncthreads();
#pragma unroll
    for (int p = 0; p < 4; ++p) {
      int idx = t + p * 256;
      int r = idx >> 4, cc = (idx & 15) * 8;
      *(bf16x8*)&lK[r][cc] = *(const bf16x8*)(Kp + (size_t)(kv0 + r) * 128 + cc);
    }
#pragma unroll
    for (int p = 0; p < 4; ++p) {
      int idx = t + p * 256;
      int r = idx >> 3, cc = (idx & 7) * 8;
      *(bf16x8*)&lV[r][cc] = *(const bf16x8*)(Vp + (size_t)r * 512 + kv0 + cc);
    }
    __syncthreads();
    bool diag = (kv0 >= q0);
#pragma unroll
    for (int mt = 0; mt < 2; ++mt) {
      f32x4 sacc[4] = {};
#pragma unroll
      for (int nt = 0; nt < 4; ++nt)
#pragma unroll
        for (int dc = 0; dc < 4; ++dc) {
          bf16x8 kf = *(const bf16x8*)&lK[nt * 16 + lr][dc * 32 + lg * 8];
          sacc[nt] = __builtin_amdgcn_mfma_f32_16x16x32_bf16(qf[mt][dc], kf, sacc[nt], 0, 0, 0);
        }
      int rbase = q0 + w * 32 + mt * 16 + lg * 4;
      if (diag) {
#pragma unroll
        for (int nt = 0; nt < 4; ++nt)
#pragma unroll
          for (int r = 0; r < 4; ++r)
            if (kv0 + nt * 16 + lr > rbase + r) sacc[nt][r] = -1e30f;
      }
#pragma unroll
      for (int r = 0; r < 4; ++r) {
        float mx = fmaxf(fmaxf(sacc[0][r], sacc[1][r]), fmaxf(sacc[2][r], sacc[3][r]));
#pragma unroll
        for (int off = 8; off; off >>= 1) mx = fmaxf(mx, __shfl_xor(mx, off));
        float mold = mrow[mt][r];
        float mnew = fmaxf(mold, mx);
        float alpha = __expf(mold - mnew);
        float ps = 0.f;
#pragma unroll
        for (int nt = 0; nt < 4; ++nt) { float p = __expf(sacc[nt][r] - mnew); sacc[nt][r] = p; ps += p; }
#pragma unroll
        for (int off = 8; off; off >>= 1) ps += __shfl_xor(ps, off);
        mrow[mt][r] = mnew;
        lrow[mt][r] = lrow[mt][r] * alpha + ps;
#pragma unroll
        for (int dt = 0; dt < 8; ++dt) o[mt][dt][r] *= alpha;
      }
#pragma unroll
      for (int nt = 0; nt < 4; ++nt)
#pragma unroll
        for (int r = 0; r < 4; ++r)
          lP[w][lg * 4 + r][nt * 16 + lr] = f2bf(sacc[nt][r]);
#pragma unroll
      for (int kc = 0; kc < 2; ++kc) {
        bf16x8 pf = *(const bf16x8*)&lP[w][lr][kc * 32 + lg * 8];
#pragma unroll
        for (int dt = 0; dt < 8; ++dt) {
          bf16x8 vf = *(const bf16x8*)&lV[dt * 16 + lr][kc * 32 + lg * 8];
          o[mt][dt] = __builtin_amdgcn_mfma_f32_16x16x32_bf16(pf, vf, o[mt][dt], 0, 0, 0);
        }
      }
    }
  }
#pragma unroll
  for (int mt = 0; mt < 2; ++mt)
#pragma unroll
    for (int r = 0; r < 4; ++r) {
      float inv = 1.f / lrow[mt][r];
      int rowg = q0 + w * 32 + mt * 16 + lg * 4 + r;
      size_t ob = ((size_t)b * 512 + rowg) * 4096 + (size_t)h * 128;
#pragma unroll
      for (int dt = 0; dt < 8; ++dt)
        Out[ob + dt * 16 + lr] = o[mt][dt][r] * inv;
    }
}

extern "C" void kernel_launch(void* const* d_in, const int* in_sizes, int n_in,
                              void* d_out, int out_size, void* d_ws, size_t ws_size,
                              hipStream_t stream) {
  const float* X = (const float*)d_in[0];     // [4,512,4096]
  const float* W = (const float*)d_in[1];     // [4096,12288]
  const float* bias = (const float*)d_in[2];  // [12288]
  float* out = (float*)d_out;
  char* ws = (char*)d_ws;
  // layout: [0,16M) Xb | [16M,112M) Wt | [112M+5.33M... qkv at 117.44M, 48M)
  u16* Xb  = (u16*)(ws);
  u16* Wt  = (u16*)(ws + 16777216);
  u16* qkv = (u16*)(ws + 117440512);
  // after GEMM, overlay Q/K/Vt on the Xb/Wt region:
  u16* Qb  = (u16*)(ws);
  u16* Kb  = (u16*)(ws + 16777216);
  u16* Vtb = (u16*)(ws + 33554432);

  k_castx<<<4096, 256, 0, stream>>>(X, Xb);
  k_wtrans<<<dim3(192, 64), 256, 0, stream>>>(W, Wt);
  k_gemm<<<dim3(96, 16), 256, 0, stream>>>(Xb, Wt, bias, qkv);
  k_rope<<<1024, 256, 0, stream>>>(qkv, Qb, Kb, Vtb);
  k_attn<<<512, 256, 0, stream>>>(Qb, Kb, Vtb, out);
}